// Round 1
// 12603.764 us; speedup vs baseline: 1.6480x; 1.6480x over previous
//
#include <hip/hip_runtime.h>

#define T_  32
#define B_  512
#define NS_ 64
#define NC_ 32
#define SZ_ 96

// ---------------- LDS layout (floats) for backward kernel ----------------
// Liveness overlays (all verified phase-disjoint):
//   V      : read P1/P3 (as V_t+1), overwritten P4 (Qxx), updated P7 (V_t)
//   FV     : rows 64..95 (FVu) written P1, dead after P2
//            rows  0..63 (FVx) written P3, dead after P4
//   XI     : = FV + 4096 (FVu region, dead after P2), written P3, read P5
//   QI     : = FV + 0    (FVx rows  0..15, dead after P4), written P5, read P6
//   KT     : = FV + 1024 (FVx rows 16..48, dead after P4), written P6, read P7
//   QLX    : Quu written P2; LDL^T factored IN PLACE in P3 (L in lower tri,
//            upper tri becomes junk that is provably never re-read)
#define L_V    0        // 64x64
#define L_F    4096     // 64x96 row-major stride 96
#define L_FV   10240    // 96x64 stride 64
#define L_QI   10240    // 32x32           (aliases FV, P5-P6)
#define L_KT   11264    // 64x33           (aliases FV, P6-P7)
#define L_XI   14336    // 32x33 = FV+4096 (aliases FVu, P3-P5)
#define L_QXU  16384    // 64x33
#define L_QLX  18496    // 32x33 Quu / in-place LDL
#define L_XU   19552    // 96
#define L_CX   19648    // 96 (C @ xu accumulator)
#define L_QV   19744    // 96
#define L_VA   19840    // 64 v ping
#define L_VB   19904    // 64 v pong
#define L_DINV 19968    // 32
#define L_KK   20000    // 32
#define L_OC   20032    // 1
#define LDS_FLOATS 20033   // 80132 B <= 81920 B  -> 2 blocks/CU

#define KT_ELEMS ((size_t)T_ * B_ * (size_t)(NC_ * NS_))   // 33,554,432
#define KS_ELEMS ((size_t)T_ * B_ * NC_)                   // 524,288

__device__ __forceinline__ float wred64(float v) {
    #pragma unroll
    for (int m = 1; m < 64; m <<= 1) v += __shfl_xor(v, m);
    return v;
}
__device__ __forceinline__ float wred32(float v) {
    #pragma unroll
    for (int m = 1; m < 32; m <<= 1) v += __shfl_xor(v, m);
    return v;
}

// =====================  BACKWARD (Riccati) KERNEL  =====================
// 512 threads, LDS 80.1 KB, VGPR pinned <=128 (4 waves/SIMD => 2 blocks/CU)
__global__ __launch_bounds__(512, 4)
void lqr_bwd(const float* __restrict__ x, const float* __restrict__ u,
             const float* __restrict__ C, const float* __restrict__ c,
             const float* __restrict__ F,
             float* __restrict__ KTws, float* __restrict__ ksws,
             float* __restrict__ J0ws)
{
    extern __shared__ float sm[];
    const int b   = blockIdx.x;
    const int tid = threadIdx.x;
    const int wv  = tid >> 6;
    const int ln  = tid & 63;

    // init V=0, v=0, old_cost=0
    for (int i = tid; i < 4096; i += 512) sm[L_V + i] = 0.f;
    if (tid < 64) sm[L_VA + tid] = 0.f;
    if (tid == 0) sm[L_OC] = 0.f;
    __syncthreads();

    int par = 0;
    for (int t = T_ - 1; t >= 0; --t) {
        const float* vc = sm + (par ? L_VB : L_VA);
        float*       vn = sm + (par ? L_VA : L_VB);
        const size_t tb = (size_t)t * B_ + b;
        const float* Cg = C + tb * (size_t)(SZ_ * SZ_);
        const float* cg = c + tb * SZ_;
        const float* Fg = F + tb * (size_t)(NS_ * SZ_);

        // ---- P0: zero Cx, load xu, stage F ----
        if (tid < 96) sm[L_CX + tid] = 0.f;
        if (tid < 64) sm[L_XU + tid] = x[tb * NS_ + tid];
        else if (tid < 96) sm[L_XU + tid] = u[tb * NC_ + (tid - 64)];
        {
            const float4* Fg4 = reinterpret_cast<const float4*>(Fg);
            float4* Fs4 = reinterpret_cast<float4*>(sm + L_F);
            #pragma unroll
            for (int r = 0; r < 3; ++r) Fs4[tid + 512 * r] = Fg4[tid + 512 * r];
        }
        __syncthreads();

        // ---- P1: FVu = rows 64..95 of F^T V  (4 rows per wave) ----
        {
            const int a0 = 4 * wv;
            float ac0 = 0.f, ac1 = 0.f, ac2 = 0.f, ac3 = 0.f;
            #pragma unroll 4
            for (int n = 0; n < 64; ++n) {
                float vm = sm[L_V + n * 64 + ln];
                float4 fb = *reinterpret_cast<const float4*>(&sm[L_F + n * 96 + 64 + a0]);
                ac0 += fb.x * vm; ac1 += fb.y * vm; ac2 += fb.z * vm; ac3 += fb.w * vm;
            }
            sm[L_FV + (64 + a0 + 0) * 64 + ln] = ac0;
            sm[L_FV + (64 + a0 + 1) * 64 + ln] = ac1;
            sm[L_FV + (64 + a0 + 2) * 64 + ln] = ac2;
            sm[L_FV + (64 + a0 + 3) * 64 + ln] = ac3;
        }
        __syncthreads();

        // ---- P2: Quu = Cuu + FVu*Fu  (+ Cx u-u direct part) ----
        {
            const int h = ln >> 5, b2 = ln & 31;
            const int a0 = 4 * wv + 2 * h;
            float q0 = 0.f, q1 = 0.f;
            for (int m = 0; m < 64; ++m) {
                float fcol = sm[L_F + m * 96 + 64 + b2];
                q0 += sm[L_FV + (64 + a0 + 0) * 64 + m] * fcol;
                q1 += sm[L_FV + (64 + a0 + 1) * 64 + m] * fcol;
            }
            float c0v = Cg[(64 + a0) * 96 + 64 + b2];
            float c1v = Cg[(64 + a0 + 1) * 96 + 64 + b2];
            q0 += c0v; q1 += c1v;
            sm[L_QLX + (a0 + 0) * 33 + b2] = q0;
            sm[L_QLX + (a0 + 1) * 33 + b2] = q1;
            float xub = sm[L_XU + 64 + b2];
            float p0 = wred32(c0v * xub);
            float p1 = wred32(c1v * xub);
            if (b2 == 0) { sm[L_CX + 64 + a0] = p0; sm[L_CX + 64 + a0 + 1] = p1; }
        }
        __syncthreads();

        // ---- P3: wave0 lanes<32 = in-LDS LDL + Linv ; waves1-7 = FVx ----
        if (tid < 32) {
            // In-place LDL^T on M = sm[L_QLX] (stride 33). Zero per-thread
            // arrays -> no spill risk. Lane tid owns row tid.
            #pragma unroll 1
            for (int k = 0; k < 32; ++k) {
                float di = 1.0f / sm[L_QLX + k * 33 + k];
                if (tid == 0) sm[L_DINV + k] = di;
                float lik = sm[L_QLX + tid * 33 + k] * di;
                if (tid > k) {
                    sm[L_QLX + tid * 33 + k] = lik;   // store L below diagonal
                    for (int j = k + 1; j < 32; ++j)
                        sm[L_QLX + tid * 33 + j] -= lik * sm[L_QLX + k * 33 + j];
                }
            }
            // Xi = L^{-1}, column tid, forward substitution fully in LDS
            sm[L_XI + tid] = (tid == 0) ? 1.f : 0.f;
            #pragma unroll 1
            for (int i = 1; i < 32; ++i) {
                float s = (i == tid) ? 1.f : 0.f;
                for (int j = 0; j < i; ++j)
                    s -= sm[L_QLX + i * 33 + j] * sm[L_XI + j * 33 + tid];
                sm[L_XI + i * 33 + tid] = s;
            }
        } else if (wv >= 1) {
            // FVx rows rstart..rstart+9 (dup rows write identical values)
            const int w2 = wv - 1;
            const int rstart = 9 * w2;
            float accf[10];
            #pragma unroll
            for (int r = 0; r < 10; ++r) accf[r] = 0.f;
            for (int n = 0; n < 64; ++n) {
                float vm = sm[L_V + n * 64 + ln];
                #pragma unroll
                for (int r = 0; r < 10; ++r)
                    accf[r] += sm[L_F + n * 96 + rstart + r] * vm;
            }
            #pragma unroll
            for (int r = 0; r < 10; ++r)
                sm[L_FV + (rstart + r) * 64 + ln] = accf[r];
        }
        __syncthreads();

        // ---- P4: Qxx -> V in-place (8 rows/wave) ; Qxu (4 rows/half-wave) ----
        {
            float acc2[8];
            #pragma unroll
            for (int r = 0; r < 8; ++r) acc2[r] = 0.f;
            #pragma unroll
            for (int mc = 0; mc < 4; ++mc) {
                float fc[16];
                #pragma unroll
                for (int q = 0; q < 16; ++q) fc[q] = sm[L_F + (16 * mc + q) * 96 + ln];
                #pragma unroll
                for (int r = 0; r < 8; ++r) {
                    const float* fv = &sm[L_FV + (8 * wv + r) * 64 + 16 * mc];
                    float4 b0 = *reinterpret_cast<const float4*>(fv);
                    float4 b1 = *reinterpret_cast<const float4*>(fv + 4);
                    float4 b2 = *reinterpret_cast<const float4*>(fv + 8);
                    float4 b3 = *reinterpret_cast<const float4*>(fv + 12);
                    acc2[r] += b0.x*fc[0]  + b0.y*fc[1]  + b0.z*fc[2]  + b0.w*fc[3]
                             + b1.x*fc[4]  + b1.y*fc[5]  + b1.z*fc[6]  + b1.w*fc[7]
                             + b2.x*fc[8]  + b2.y*fc[9]  + b2.z*fc[10] + b2.w*fc[11]
                             + b3.x*fc[12] + b3.y*fc[13] + b3.z*fc[14] + b3.w*fc[15];
                }
            }
            float xuj = sm[L_XU + ln];
            #pragma unroll
            for (int r = 0; r < 8; ++r) {
                int i = 8 * wv + r;
                float cv = Cg[i * 96 + ln];
                sm[L_V + i * 64 + ln] = acc2[r] + cv;   // V dead -> Qxx in place
                float px = wred64(cv * xuj);
                if (ln == 0) atomicAdd(&sm[L_CX + i], px);
            }
        }
        {
            const int hw = tid >> 5, a2 = tid & 31;
            float acc3[4] = {0.f, 0.f, 0.f, 0.f};
            for (int m = 0; m < 64; ++m) {
                float fcol = sm[L_F + m * 96 + 64 + a2];
                #pragma unroll
                for (int r = 0; r < 4; ++r)
                    acc3[r] += sm[L_FV + (4 * hw + r) * 64 + m] * fcol;
            }
            float xua = sm[L_XU + 64 + a2];
            float pu = 0.f;
            #pragma unroll
            for (int r = 0; r < 4; ++r) {
                int i = 4 * hw + r;
                float cv = Cg[i * 96 + 64 + a2];
                sm[L_QXU + i * 33 + a2] = acc3[r] + cv;
                float px = wred32(cv * xua);
                if (a2 == 0) atomicAdd(&sm[L_CX + i], px);
                pu += cv * sm[L_XU + i];                 // symmetric transpose part
            }
            atomicAdd(&sm[L_CX + 64 + a2], pu);
        }
        __syncthreads();

        // ---- P5: QI = Xi^T Dinv Xi ; q vector ; old_cost ----
        {
            const int b2 = tid & 31, ag = tid >> 5;   // ag 0..15
            float s0 = 0.f, s1 = 0.f;
            for (int cc = 0; cc < 32; ++cc) {
                float t1 = sm[L_DINV + cc] * sm[L_XI + cc * 33 + b2];
                s0 += sm[L_XI + cc * 33 + ag] * t1;
                s1 += sm[L_XI + cc * 33 + ag + 16] * t1;
            }
            sm[L_QI + ag * 32 + b2] = s0;
            sm[L_QI + (ag + 16) * 32 + b2] = s1;
        }
        if (tid >= 96 && tid < 192) {
            int i = tid - 96;
            float s = sm[L_CX + i] + cg[i];
            for (int n = 0; n < 64; ++n)
                s += sm[L_F + n * 96 + i] * vc[n];
            sm[L_QV + i] = s;
        }
        if (tid >= 192 && tid < 288) {
            int i = tid - 192;
            float p = sm[L_XU + i] * (0.5f * sm[L_CX + i] + cg[i]);
            if (tid < 256) { p = wred64(p); if (tid == 192) atomicAdd(&sm[L_OC], p); }
            else           { p = wred32(p); if (tid == 256) atomicAdd(&sm[L_OC], p); }
        }
        __syncthreads();

        // ---- P6: K^T = -Qxu * Quuinv ; k = -Quuinv*qu ----
        {
            const int a = tid & 31, jg = tid >> 5;  // jg 0..15
            float acc[4] = {0.f, 0.f, 0.f, 0.f};
            for (int b2 = 0; b2 < 32; ++b2) {
                float qb = sm[L_QI + b2 * 32 + a];
                #pragma unroll
                for (int r = 0; r < 4; ++r)
                    acc[r] -= sm[L_QXU + (jg + 16 * r) * 33 + b2] * qb;
            }
            float* KTg = KTws + tb * 2048;
            #pragma unroll
            for (int r = 0; r < 4; ++r) {
                int j = jg + 16 * r;
                sm[L_KT + j * 33 + a] = acc[r];
                KTg[j * 32 + a] = acc[r];
            }
        }
        if (tid >= 448 && tid < 480) {
            int a = tid - 448;
            float s = 0.f;
            for (int b2 = 0; b2 < 32; ++b2)
                s -= sm[L_QI + b2 * 32 + a] * sm[L_QV + 64 + b2];  // QI symmetric
            sm[L_KK + a] = s;
            ksws[tb * 32 + a] = s;
        }
        __syncthreads();

        // ---- P7: V += Qxu*K (in place) ; v_new = qx + Qxu*k ----
        {
            float acc[8];
            #pragma unroll
            for (int rr = 0; rr < 8; ++rr) acc[rr] = sm[L_V + (8 * wv + rr) * 64 + ln];
            for (int a = 0; a < 32; ++a) {
                float ktv = sm[L_KT + ln * 33 + a];
                #pragma unroll
                for (int rr = 0; rr < 8; ++rr)
                    acc[rr] += sm[L_QXU + (8 * wv + rr) * 33 + a] * ktv;
            }
            #pragma unroll
            for (int rr = 0; rr < 8; ++rr) sm[L_V + (8 * wv + rr) * 64 + ln] = acc[rr];
        }
        if (tid < 64) {
            float s = sm[L_QV + tid];
            for (int a = 0; a < 32; ++a)
                s += sm[L_QXU + tid * 33 + a] * sm[L_KK + a];
            vn[tid] = s;
        }
        __syncthreads();
        par ^= 1;
    }
    if (tid == 0) J0ws[b] = sm[L_OC];
}

// =====================  FORWARD (rollout + line search) KERNEL  =====================
__global__ __launch_bounds__(256)
void lqr_fwd(const float* __restrict__ x, const float* __restrict__ u,
             const float* __restrict__ xinit,
             const float* __restrict__ C, const float* __restrict__ c,
             const float* __restrict__ F,
             const float* __restrict__ KTws, const float* __restrict__ ksws,
             const float* __restrict__ J0ws, float* __restrict__ out)
{
    __shared__ __align__(16) float Fp[64 * 97];
    __shared__ __align__(16) float KTl[2048];
    __shared__ float kv[32], uL[32], cL[96], xn[64];
    __shared__ float dx0[64], dx1[64], nxt0[64], nxt1[64];
    __shared__ __align__(16) float xu0a[32 * 96];   // alpha=0 trajectory [t][s]
    __shared__ __align__(16) float dxua[32 * 96];   // traj(1) - traj(0)
    __shared__ float red[6];

    const int b = blockIdx.x;
    const int tid = threadIdx.x;

    if (tid < 64) {
        float xi = xinit[(size_t)b * 64 + tid];
        xu0a[tid] = xi; dxua[tid] = 0.f;
        dx0[tid] = 0.f; dx1[tid] = 0.f;
    }
    if (tid < 6) red[tid] = 0.f;
    float saa = 0.f, sab = 0.f, sbb = 0.f, cpa = 0.f, cpb = 0.f;
    __syncthreads();

    for (int t = 0; t < T_; ++t) {
        const size_t tb = (size_t)t * B_ + b;
        // ---- phase A: stage F, K^T, k, u, c, x_next ----
        {
            const float4* Fg4 = reinterpret_cast<const float4*>(F + tb * (size_t)(64 * 96));
            #pragma unroll
            for (int r = 0; r < 6; ++r) {
                int f4i = tid + 256 * r;
                float4 v = Fg4[f4i];
                int n = f4i / 24, s0 = (f4i % 24) * 4;
                float* p = &Fp[n * 97 + s0];
                p[0] = v.x; p[1] = v.y; p[2] = v.z; p[3] = v.w;
            }
            const float4* Kg4 = reinterpret_cast<const float4*>(KTws + tb * 2048);
            float4* Kl4 = reinterpret_cast<float4*>(KTl);
            Kl4[tid] = Kg4[tid];
            Kl4[tid + 256] = Kg4[tid + 256];
            if (tid < 32) kv[tid] = ksws[tb * 32 + tid];
            else if (tid < 64) uL[tid - 32] = u[tb * 32 + (tid - 32)];
            else if (tid < 160) cL[tid - 64] = c[tb * 96 + (tid - 64)];
            else if (tid < 224) {
                int tn = (t < 31) ? (t + 1) : 31;
                xn[tid - 160] = x[((size_t)tn * B_ + b) * 64 + (tid - 160)];
            }
        }
        __syncthreads();
        // ---- phase B: controls nu0 / nu1 ----
        if (tid < 64) {
            const int h = tid >> 5, a = tid & 31;
            const float* dxp = h ? dx1 : dx0;
            float s = uL[a] + (h ? kv[a] : 0.f);
            for (int j = 0; j < 64; ++j)
                s += KTl[j * 32 + a] * dxp[j];
            float nu0v = __shfl(s, a);    // lane a (h=0) holds nu0[a]
            if (h == 0) xu0a[t * 96 + 64 + a] = s;
            else        dxua[t * 96 + 64 + a] = s - nu0v;
        }
        __syncthreads();
        // ---- phase C: quadratic forms over C + dynamics matvecs + c-dots ----
        {
            const float4* Cg4 = reinterpret_cast<const float4*>(C + tb * (size_t)(96 * 96));
            #pragma unroll
            for (int r = 0; r < 9; ++r) {
                int e4 = tid + 256 * r;
                int i = e4 / 24, j0 = (e4 % 24) * 4;
                float4 cv = Cg4[e4];
                float4 av = *reinterpret_cast<const float4*>(&xu0a[t * 96 + j0]);
                float4 bv = *reinterpret_cast<const float4*>(&dxua[t * 96 + j0]);
                float ai = xu0a[t * 96 + i], bi = dxua[t * 96 + i];
                float da = cv.x * av.x + cv.y * av.y + cv.z * av.z + cv.w * av.w;
                float db = cv.x * bv.x + cv.y * bv.y + cv.z * bv.z + cv.w * bv.w;
                saa += ai * da; sab += ai * db; sbb += bi * db;
            }
        }
        if (tid < 128) {
            const int h = tid >> 6, n = tid & 63;
            float s = 0.f;
            if (h == 0) {
                for (int ss = 0; ss < 96; ++ss) s += Fp[n * 97 + ss] * xu0a[t * 96 + ss];
                nxt0[n] = s;
            } else {
                for (int ss = 0; ss < 96; ++ss) s += Fp[n * 97 + ss] * (xu0a[t * 96 + ss] + dxua[t * 96 + ss]);
                nxt1[n] = s;
            }
        } else if (tid < 224) {
            int i = tid - 128;
            cpa += cL[i] * xu0a[t * 96 + i];
            cpb += cL[i] * dxua[t * 96 + i];
        }
        __syncthreads();
        // ---- phase D: advance states ----
        if (tid < 128) {
            const int h = tid >> 6, n = tid & 63;
            if (h == 0) {
                float v0 = nxt0[n];
                dx0[n] = v0 - xn[n];
                if (t < 31) xu0a[(t + 1) * 96 + n] = v0;
            } else {
                float v1 = nxt1[n];
                dx1[n] = v1 - xn[n];
                if (t < 31) dxua[(t + 1) * 96 + n] = v1 - nxt0[n];
            }
        }
        __syncthreads();
    }

    // ---- reduce quadratic coefficients ----
    saa = wred64(saa); sab = wred64(sab); sbb = wred64(sbb);
    cpa = wred64(cpa); cpb = wred64(cpb);
    if ((tid & 63) == 0) {
        atomicAdd(&red[0], saa); atomicAdd(&red[1], sab); atomicAdd(&red[2], sbb);
        atomicAdd(&red[3], cpa); atomicAdd(&red[4], cpb);
    }
    __syncthreads();

    // ---- line search on quadratic J(alpha), then write outputs ----
    float c0 = 0.5f * red[0] + red[3];
    float c1 = red[1] + red[4];
    float c2 = 0.5f * red[2];
    float J0 = J0ws[b];
    float al = 1.f;
    #pragma unroll
    for (int it = 0; it < 3; ++it) {
        float Jc = c0 + al * (c1 + al * c2);
        if (Jc > J0) al *= 0.5f;
    }
    float Jfin = c0 + al * (c1 + al * c2);

    for (int e = tid; e < 3072; e += 256) {
        int tt = e / 96, s = e % 96;
        float val = xu0a[e] + al * dxua[e];
        if (s < 64) out[(size_t)tt * (B_ * 64) + (size_t)b * 64 + s] = val;
        else        out[1048576 + (size_t)tt * (B_ * 32) + (size_t)b * 32 + (s - 64)] = val;
    }
    if (tid == 0) out[1572864 + b] = Jfin;
}

// =====================  LAUNCH  =====================
extern "C" void kernel_launch(void* const* d_in, const int* in_sizes, int n_in,
                              void* d_out, int out_size, void* d_ws, size_t ws_size,
                              hipStream_t stream)
{
    const float* x  = (const float*)d_in[0];
    const float* u  = (const float*)d_in[1];
    const float* xi = (const float*)d_in[2];
    const float* C  = (const float*)d_in[3];
    const float* c  = (const float*)d_in[4];
    const float* F  = (const float*)d_in[5];
    float* out  = (float*)d_out;
    float* KTws = (float*)d_ws;
    float* ksws = KTws + KT_ELEMS;
    float* J0ws = ksws + KS_ELEMS;

    const int ldsB = LDS_FLOATS * 4;  // 80,132 B dynamic LDS -> 2 blocks/CU
    (void)hipFuncSetAttribute(reinterpret_cast<const void*>(lqr_bwd),
                              hipFuncAttributeMaxDynamicSharedMemorySize, ldsB);

    hipLaunchKernelGGL(lqr_bwd, dim3(512), dim3(512), ldsB, stream,
                       x, u, C, c, F, KTws, ksws, J0ws);
    hipLaunchKernelGGL(lqr_fwd, dim3(512), dim3(256), 0, stream,
                       x, u, xi, C, c, F, KTws, ksws, J0ws, out);
}

// Round 2
// 5898.219 us; speedup vs baseline: 3.5216x; 2.1369x over previous
//
#include <hip/hip_runtime.h>

#define T_  32
#define B_  512
#define NS_ 64
#define NC_ 32
#define SZ_ 96

// ---------------- LDS layout (floats) for backward kernel ----------------
// Liveness overlays (all verified phase-disjoint):
//   V      : read P1/P3 (as V_t+1), overwritten P4 (Qxx), updated P7 (V_t)
//   FV     : rows 64..95 (FVu) written P1, dead after P2
//            rows  0..63 (FVx) written P3, dead after P4
//   XI     : = FV + 4096 (FVu region, dead after P2), written P3, read P5
//   QI     : = FV + 0    (FVx rows  0..15, dead after P4), written P5, read P6
//   KT     : = FV + 1024 (FVx rows 16..48, dead after P4), written P6, read P7
//   QLX    : Quu written P2; LDL^T factored IN PLACE in P3
#define L_V    0        // 64x64
#define L_F    4096     // 64x96 row-major stride 96
#define L_FV   10240    // 96x64 stride 64
#define L_QI   10240    // 32x32           (aliases FV, P5-P6)
#define L_KT   11264    // 64x33           (aliases FV, P6-P7)
#define L_XI   14336    // 32x33 = FV+4096 (aliases FVu, P3-P5)
#define L_QXU  16384    // 64x33
#define L_QLX  18496    // 32x33 Quu / in-place LDL
#define L_XU   19552    // 96
#define L_CX   19648    // 96 (C @ xu accumulator)
#define L_QV   19744    // 96
#define L_VA   19840    // 64 v ping
#define L_VB   19904    // 64 v pong
#define L_DINV 19968    // 32
#define L_KK   20000    // 32
#define L_OC   20032    // 1
#define LDS_FLOATS 20033   // 80132 B <= 81920 B  -> 2 blocks/CU

#define KT_ELEMS ((size_t)T_ * B_ * (size_t)(NC_ * NS_))   // 33,554,432
#define KS_ELEMS ((size_t)T_ * B_ * NC_)                   // 524,288

__device__ __forceinline__ float wred64(float v) {
    #pragma unroll
    for (int m = 1; m < 64; m <<= 1) v += __shfl_xor(v, m);
    return v;
}
__device__ __forceinline__ float wred32(float v) {
    #pragma unroll
    for (int m = 1; m < 32; m <<= 1) v += __shfl_xor(v, m);
    return v;
}

// =====================  BACKWARD (Riccati) KERNEL  =====================
// 512 threads, LDS 80.1 KB -> 2 blocks/CU. Peak live regs kept ~<=32 floats
// everywhere so even a 64-VGPR compiler budget cannot spill.
__global__ __launch_bounds__(512, 4)
void lqr_bwd(const float* __restrict__ x, const float* __restrict__ u,
             const float* __restrict__ C, const float* __restrict__ c,
             const float* __restrict__ F,
             float* __restrict__ KTws, float* __restrict__ ksws,
             float* __restrict__ J0ws)
{
    extern __shared__ float sm[];
    const int b   = blockIdx.x;
    const int tid = threadIdx.x;
    const int wv  = tid >> 6;
    const int ln  = tid & 63;

    // init V=0, v=0, old_cost=0
    for (int i = tid; i < 4096; i += 512) sm[L_V + i] = 0.f;
    if (tid < 64) sm[L_VA + tid] = 0.f;
    if (tid == 0) sm[L_OC] = 0.f;
    __syncthreads();

    int par = 0;
    for (int t = T_ - 1; t >= 0; --t) {
        const float* vc = sm + (par ? L_VB : L_VA);
        float*       vn = sm + (par ? L_VA : L_VB);
        const size_t tb = (size_t)t * B_ + b;
        const float* Cg = C + tb * (size_t)(SZ_ * SZ_);
        const float* cg = c + tb * SZ_;
        const float* Fg = F + tb * (size_t)(NS_ * SZ_);

        // ---- P0: zero Cx, load xu, stage F ----
        if (tid < 96) sm[L_CX + tid] = 0.f;
        if (tid < 64) sm[L_XU + tid] = x[tb * NS_ + tid];
        else if (tid < 96) sm[L_XU + tid] = u[tb * NC_ + (tid - 64)];
        {
            const float4* Fg4 = reinterpret_cast<const float4*>(Fg);
            float4* Fs4 = reinterpret_cast<float4*>(sm + L_F);
            #pragma unroll
            for (int r = 0; r < 3; ++r) Fs4[tid + 512 * r] = Fg4[tid + 512 * r];
        }
        __syncthreads();

        // ---- P1: FVu = rows 64..95 of F^T V  (4 rows per wave) ----
        {
            const int a0 = 4 * wv;
            float ac0 = 0.f, ac1 = 0.f, ac2 = 0.f, ac3 = 0.f;
            #pragma unroll 4
            for (int n = 0; n < 64; ++n) {
                float vm = sm[L_V + n * 64 + ln];
                float4 fb = *reinterpret_cast<const float4*>(&sm[L_F + n * 96 + 64 + a0]);
                ac0 += fb.x * vm; ac1 += fb.y * vm; ac2 += fb.z * vm; ac3 += fb.w * vm;
            }
            sm[L_FV + (64 + a0 + 0) * 64 + ln] = ac0;
            sm[L_FV + (64 + a0 + 1) * 64 + ln] = ac1;
            sm[L_FV + (64 + a0 + 2) * 64 + ln] = ac2;
            sm[L_FV + (64 + a0 + 3) * 64 + ln] = ac3;
        }
        __syncthreads();

        // ---- P2: Quu = Cuu + FVu*Fu  (+ Cx u-u direct part) ----
        {
            const int h = ln >> 5, b2 = ln & 31;
            const int a0 = 4 * wv + 2 * h;
            float q0 = 0.f, q1 = 0.f;
            for (int m = 0; m < 64; ++m) {
                float fcol = sm[L_F + m * 96 + 64 + b2];
                q0 += sm[L_FV + (64 + a0 + 0) * 64 + m] * fcol;
                q1 += sm[L_FV + (64 + a0 + 1) * 64 + m] * fcol;
            }
            float c0v = Cg[(64 + a0) * 96 + 64 + b2];
            float c1v = Cg[(64 + a0 + 1) * 96 + 64 + b2];
            q0 += c0v; q1 += c1v;
            sm[L_QLX + (a0 + 0) * 33 + b2] = q0;
            sm[L_QLX + (a0 + 1) * 33 + b2] = q1;
            float xub = sm[L_XU + 64 + b2];
            float p0 = wred32(c0v * xub);
            float p1 = wred32(c1v * xub);
            if (b2 == 0) { sm[L_CX + 64 + a0] = p0; sm[L_CX + 64 + a0 + 1] = p1; }
        }
        __syncthreads();

        // ---- P3: wave0 lanes<32 = in-LDS LDL + Linv ; waves1-7 = FVx ----
        if (tid < 32) {
            // In-place LDL^T on M = sm[L_QLX] (stride 33), zero thread arrays.
            #pragma unroll 1
            for (int k = 0; k < 32; ++k) {
                float di = 1.0f / sm[L_QLX + k * 33 + k];
                if (tid == 0) sm[L_DINV + k] = di;
                float lik = sm[L_QLX + tid * 33 + k] * di;
                if (tid > k) {
                    sm[L_QLX + tid * 33 + k] = lik;   // store L below diagonal
                    for (int j = k + 1; j < 32; ++j)
                        sm[L_QLX + tid * 33 + j] -= lik * sm[L_QLX + k * 33 + j];
                }
            }
            // Xi = L^{-1}, column tid, forward substitution fully in LDS
            sm[L_XI + tid] = (tid == 0) ? 1.f : 0.f;
            #pragma unroll 1
            for (int i = 1; i < 32; ++i) {
                float s = (i == tid) ? 1.f : 0.f;
                for (int j = 0; j < i; ++j)
                    s -= sm[L_QLX + i * 33 + j] * sm[L_XI + j * 33 + tid];
                sm[L_XI + i * 33 + tid] = s;
            }
        } else if (wv >= 1) {
            // FVx rows rstart..rstart+9 (dup rows write identical values)
            const int w2 = wv - 1;
            const int rstart = 9 * w2;
            float accf[10];
            #pragma unroll
            for (int r = 0; r < 10; ++r) accf[r] = 0.f;
            for (int n = 0; n < 64; ++n) {
                float vm = sm[L_V + n * 64 + ln];
                #pragma unroll
                for (int r = 0; r < 10; ++r)
                    accf[r] += sm[L_F + n * 96 + rstart + r] * vm;
            }
            #pragma unroll
            for (int r = 0; r < 10; ++r)
                sm[L_FV + (rstart + r) * 64 + ln] = accf[r];
        }
        __syncthreads();

        // ---- P4: Qxx -> V in-place (8 rows/wave) ; Qxu (4 rows/half-wave) ----
        // m processed in chunks of 8 to cap live registers (~30 floats peak):
        // fc[8] + acc2[8] + 2 float4 temps + addressing. No spill at 64-VGPR.
        {
            float acc2[8];
            #pragma unroll
            for (int r = 0; r < 8; ++r) acc2[r] = 0.f;
            #pragma unroll 1
            for (int mc = 0; mc < 8; ++mc) {
                float fc[8];
                #pragma unroll
                for (int q = 0; q < 8; ++q) fc[q] = sm[L_F + (8 * mc + q) * 96 + ln];
                #pragma unroll
                for (int r = 0; r < 8; ++r) {
                    const float* fv = &sm[L_FV + (8 * wv + r) * 64 + 8 * mc];
                    float4 b0 = *reinterpret_cast<const float4*>(fv);
                    float4 b1 = *reinterpret_cast<const float4*>(fv + 4);
                    acc2[r] += b0.x*fc[0] + b0.y*fc[1] + b0.z*fc[2] + b0.w*fc[3]
                             + b1.x*fc[4] + b1.y*fc[5] + b1.z*fc[6] + b1.w*fc[7];
                }
            }
            float xuj = sm[L_XU + ln];
            #pragma unroll 1
            for (int r = 0; r < 8; ++r) {
                int i = 8 * wv + r;
                float cv = Cg[i * 96 + ln];
                sm[L_V + i * 64 + ln] = acc2[r] + cv;   // V dead -> Qxx in place
                float px = wred64(cv * xuj);
                if (ln == 0) atomicAdd(&sm[L_CX + i], px);
            }
        }
        {
            const int hw = tid >> 5, a2 = tid & 31;
            float acc3[4] = {0.f, 0.f, 0.f, 0.f};
            for (int m = 0; m < 64; ++m) {
                float fcol = sm[L_F + m * 96 + 64 + a2];
                #pragma unroll
                for (int r = 0; r < 4; ++r)
                    acc3[r] += sm[L_FV + (4 * hw + r) * 64 + m] * fcol;
            }
            float xua = sm[L_XU + 64 + a2];
            float pu = 0.f;
            #pragma unroll 1
            for (int r = 0; r < 4; ++r) {
                int i = 4 * hw + r;
                float cv = Cg[i * 96 + 64 + a2];
                sm[L_QXU + i * 33 + a2] = acc3[r] + cv;
                float px = wred32(cv * xua);
                if (a2 == 0) atomicAdd(&sm[L_CX + i], px);
                pu += cv * sm[L_XU + i];                 // symmetric transpose part
            }
            atomicAdd(&sm[L_CX + 64 + a2], pu);
        }
        __syncthreads();

        // ---- P5: QI = Xi^T Dinv Xi ; q vector ; old_cost ----
        {
            const int b2 = tid & 31, ag = tid >> 5;   // ag 0..15
            float s0 = 0.f, s1 = 0.f;
            for (int cc = 0; cc < 32; ++cc) {
                float t1 = sm[L_DINV + cc] * sm[L_XI + cc * 33 + b2];
                s0 += sm[L_XI + cc * 33 + ag] * t1;
                s1 += sm[L_XI + cc * 33 + ag + 16] * t1;
            }
            sm[L_QI + ag * 32 + b2] = s0;
            sm[L_QI + (ag + 16) * 32 + b2] = s1;
        }
        if (tid >= 96 && tid < 192) {
            int i = tid - 96;
            float s = sm[L_CX + i] + cg[i];
            for (int n = 0; n < 64; ++n)
                s += sm[L_F + n * 96 + i] * vc[n];
            sm[L_QV + i] = s;
        }
        if (tid >= 192 && tid < 288) {
            int i = tid - 192;
            float p = sm[L_XU + i] * (0.5f * sm[L_CX + i] + cg[i]);
            if (tid < 256) { p = wred64(p); if (tid == 192) atomicAdd(&sm[L_OC], p); }
            else           { p = wred32(p); if (tid == 256) atomicAdd(&sm[L_OC], p); }
        }
        __syncthreads();

        // ---- P6: K^T = -Qxu * Quuinv ; k = -Quuinv*qu ----
        {
            const int a = tid & 31, jg = tid >> 5;  // jg 0..15
            float acc[4] = {0.f, 0.f, 0.f, 0.f};
            for (int b2 = 0; b2 < 32; ++b2) {
                float qb = sm[L_QI + b2 * 32 + a];
                #pragma unroll
                for (int r = 0; r < 4; ++r)
                    acc[r] -= sm[L_QXU + (jg + 16 * r) * 33 + b2] * qb;
            }
            float* KTg = KTws + tb * 2048;
            #pragma unroll
            for (int r = 0; r < 4; ++r) {
                int j = jg + 16 * r;
                sm[L_KT + j * 33 + a] = acc[r];
                __builtin_nontemporal_store(acc[r], &KTg[j * 32 + a]);
            }
        }
        if (tid >= 448 && tid < 480) {
            int a = tid - 448;
            float s = 0.f;
            for (int b2 = 0; b2 < 32; ++b2)
                s -= sm[L_QI + b2 * 32 + a] * sm[L_QV + 64 + b2];  // QI symmetric
            sm[L_KK + a] = s;
            __builtin_nontemporal_store(s, &ksws[tb * 32 + a]);
        }
        __syncthreads();

        // ---- P7: V += Qxu*K (in place) ; v_new = qx + Qxu*k ----
        {
            float acc[8];
            #pragma unroll
            for (int rr = 0; rr < 8; ++rr) acc[rr] = sm[L_V + (8 * wv + rr) * 64 + ln];
            for (int a = 0; a < 32; ++a) {
                float ktv = sm[L_KT + ln * 33 + a];
                #pragma unroll
                for (int rr = 0; rr < 8; ++rr)
                    acc[rr] += sm[L_QXU + (8 * wv + rr) * 33 + a] * ktv;
            }
            #pragma unroll
            for (int rr = 0; rr < 8; ++rr) sm[L_V + (8 * wv + rr) * 64 + ln] = acc[rr];
        }
        if (tid < 64) {
            float s = sm[L_QV + tid];
            for (int a = 0; a < 32; ++a)
                s += sm[L_QXU + tid * 33 + a] * sm[L_KK + a];
            vn[tid] = s;
        }
        __syncthreads();
        par ^= 1;
    }
    if (tid == 0) J0ws[b] = sm[L_OC];
}

// =====================  FORWARD (rollout + line search) KERNEL  =====================
__global__ __launch_bounds__(256)
void lqr_fwd(const float* __restrict__ x, const float* __restrict__ u,
             const float* __restrict__ xinit,
             const float* __restrict__ C, const float* __restrict__ c,
             const float* __restrict__ F,
             const float* __restrict__ KTws, const float* __restrict__ ksws,
             const float* __restrict__ J0ws, float* __restrict__ out)
{
    __shared__ __align__(16) float Fp[64 * 97];
    __shared__ __align__(16) float KTl[2048];
    __shared__ float kv[32], uL[32], cL[96], xn[64];
    __shared__ float dx0[64], dx1[64], nxt0[64], nxt1[64];
    __shared__ __align__(16) float xu0a[32 * 96];   // alpha=0 trajectory [t][s]
    __shared__ __align__(16) float dxua[32 * 96];   // traj(1) - traj(0)
    __shared__ float red[6];

    const int b = blockIdx.x;
    const int tid = threadIdx.x;

    if (tid < 64) {
        float xi = xinit[(size_t)b * 64 + tid];
        xu0a[tid] = xi; dxua[tid] = 0.f;
        dx0[tid] = 0.f; dx1[tid] = 0.f;
    }
    if (tid < 6) red[tid] = 0.f;
    float saa = 0.f, sab = 0.f, sbb = 0.f, cpa = 0.f, cpb = 0.f;
    __syncthreads();

    for (int t = 0; t < T_; ++t) {
        const size_t tb = (size_t)t * B_ + b;
        // ---- phase A: stage F, K^T, k, u, c, x_next ----
        {
            const float4* Fg4 = reinterpret_cast<const float4*>(F + tb * (size_t)(64 * 96));
            #pragma unroll
            for (int r = 0; r < 6; ++r) {
                int f4i = tid + 256 * r;
                float4 v = Fg4[f4i];
                int n = f4i / 24, s0 = (f4i % 24) * 4;
                float* p = &Fp[n * 97 + s0];
                p[0] = v.x; p[1] = v.y; p[2] = v.z; p[3] = v.w;
            }
            const float4* Kg4 = reinterpret_cast<const float4*>(KTws + tb * 2048);
            float4* Kl4 = reinterpret_cast<float4*>(KTl);
            Kl4[tid] = Kg4[tid];
            Kl4[tid + 256] = Kg4[tid + 256];
            if (tid < 32) kv[tid] = ksws[tb * 32 + tid];
            else if (tid < 64) uL[tid - 32] = u[tb * 32 + (tid - 32)];
            else if (tid < 160) cL[tid - 64] = c[tb * 96 + (tid - 64)];
            else if (tid < 224) {
                int tn = (t < 31) ? (t + 1) : 31;
                xn[tid - 160] = x[((size_t)tn * B_ + b) * 64 + (tid - 160)];
            }
        }
        __syncthreads();
        // ---- phase B: controls nu0 / nu1 ----
        if (tid < 64) {
            const int h = tid >> 5, a = tid & 31;
            const float* dxp = h ? dx1 : dx0;
            float s = uL[a] + (h ? kv[a] : 0.f);
            for (int j = 0; j < 64; ++j)
                s += KTl[j * 32 + a] * dxp[j];
            float nu0v = __shfl(s, a);    // lane a (h=0) holds nu0[a]
            if (h == 0) xu0a[t * 96 + 64 + a] = s;
            else        dxua[t * 96 + 64 + a] = s - nu0v;
        }
        __syncthreads();
        // ---- phase C: quadratic forms over C + dynamics matvecs + c-dots ----
        {
            const float4* Cg4 = reinterpret_cast<const float4*>(C + tb * (size_t)(96 * 96));
            #pragma unroll
            for (int r = 0; r < 9; ++r) {
                int e4 = tid + 256 * r;
                int i = e4 / 24, j0 = (e4 % 24) * 4;
                float4 cv = Cg4[e4];
                float4 av = *reinterpret_cast<const float4*>(&xu0a[t * 96 + j0]);
                float4 bv = *reinterpret_cast<const float4*>(&dxua[t * 96 + j0]);
                float ai = xu0a[t * 96 + i], bi = dxua[t * 96 + i];
                float da = cv.x * av.x + cv.y * av.y + cv.z * av.z + cv.w * av.w;
                float db = cv.x * bv.x + cv.y * bv.y + cv.z * bv.z + cv.w * bv.w;
                saa += ai * da; sab += ai * db; sbb += bi * db;
            }
        }
        if (tid < 128) {
            const int h = tid >> 6, n = tid & 63;
            float s = 0.f;
            if (h == 0) {
                for (int ss = 0; ss < 96; ++ss) s += Fp[n * 97 + ss] * xu0a[t * 96 + ss];
                nxt0[n] = s;
            } else {
                for (int ss = 0; ss < 96; ++ss) s += Fp[n * 97 + ss] * (xu0a[t * 96 + ss] + dxua[t * 96 + ss]);
                nxt1[n] = s;
            }
        } else if (tid < 224) {
            int i = tid - 128;
            cpa += cL[i] * xu0a[t * 96 + i];
            cpb += cL[i] * dxua[t * 96 + i];
        }
        __syncthreads();
        // ---- phase D: advance states ----
        if (tid < 128) {
            const int h = tid >> 6, n = tid & 63;
            if (h == 0) {
                float v0 = nxt0[n];
                dx0[n] = v0 - xn[n];
                if (t < 31) xu0a[(t + 1) * 96 + n] = v0;
            } else {
                float v1 = nxt1[n];
                dx1[n] = v1 - xn[n];
                if (t < 31) dxua[(t + 1) * 96 + n] = v1 - nxt0[n];
            }
        }
        __syncthreads();
    }

    // ---- reduce quadratic coefficients ----
    saa = wred64(saa); sab = wred64(sab); sbb = wred64(sbb);
    cpa = wred64(cpa); cpb = wred64(cpb);
    if ((tid & 63) == 0) {
        atomicAdd(&red[0], saa); atomicAdd(&red[1], sab); atomicAdd(&red[2], sbb);
        atomicAdd(&red[3], cpa); atomicAdd(&red[4], cpb);
    }
    __syncthreads();

    // ---- line search on quadratic J(alpha), then write outputs ----
    float c0 = 0.5f * red[0] + red[3];
    float c1 = red[1] + red[4];
    float c2 = 0.5f * red[2];
    float J0 = J0ws[b];
    float al = 1.f;
    #pragma unroll
    for (int it = 0; it < 3; ++it) {
        float Jc = c0 + al * (c1 + al * c2);
        if (Jc > J0) al *= 0.5f;
    }
    float Jfin = c0 + al * (c1 + al * c2);

    for (int e = tid; e < 3072; e += 256) {
        int tt = e / 96, s = e % 96;
        float val = xu0a[e] + al * dxua[e];
        if (s < 64) out[(size_t)tt * (B_ * 64) + (size_t)b * 64 + s] = val;
        else        out[1048576 + (size_t)tt * (B_ * 32) + (size_t)b * 32 + (s - 64)] = val;
    }
    if (tid == 0) out[1572864 + b] = Jfin;
}

// =====================  LAUNCH  =====================
extern "C" void kernel_launch(void* const* d_in, const int* in_sizes, int n_in,
                              void* d_out, int out_size, void* d_ws, size_t ws_size,
                              hipStream_t stream)
{
    const float* x  = (const float*)d_in[0];
    const float* u  = (const float*)d_in[1];
    const float* xi = (const float*)d_in[2];
    const float* C  = (const float*)d_in[3];
    const float* c  = (const float*)d_in[4];
    const float* F  = (const float*)d_in[5];
    float* out  = (float*)d_out;
    float* KTws = (float*)d_ws;
    float* ksws = KTws + KT_ELEMS;
    float* J0ws = ksws + KS_ELEMS;

    const int ldsB = LDS_FLOATS * 4;  // 80,132 B dynamic LDS -> 2 blocks/CU
    (void)hipFuncSetAttribute(reinterpret_cast<const void*>(lqr_bwd),
                              hipFuncAttributeMaxDynamicSharedMemorySize, ldsB);

    hipLaunchKernelGGL(lqr_bwd, dim3(512), dim3(512), ldsB, stream,
                       x, u, C, c, F, KTws, ksws, J0ws);
    hipLaunchKernelGGL(lqr_fwd, dim3(512), dim3(256), 0, stream,
                       x, u, xi, C, c, F, KTws, ksws, J0ws, out);
}